// Round 9
// baseline (27091.364 us; speedup 1.0000x reference)
//
#include <hip/hip_runtime.h>
#include <hip/hip_bf16.h>

#define S_LEN 2048
#define BATCH 64
#define HID   512
#define GATES 2048   // 4*HID
#define DIN   512

typedef __attribute__((ext_vector_type(8))) short short8v;
typedef __attribute__((ext_vector_type(4))) float f32x4;
typedef __attribute__((ext_vector_type(4))) unsigned uint4v;

__device__ inline unsigned short f2bf(float f) {
  union { float f; unsigned u; } a; a.f = f;
  unsigned r = a.u + 0x7fffu + ((a.u >> 16) & 1u);
  return (unsigned short)(r >> 16);
}
__device__ inline float bf2f(unsigned short h) {
  union { unsigned u; float f; } a; a.u = ((unsigned)h) << 16; return a.f;
}

// ---------- kernel 1: split x (fp32) -> bf16 hi + lo ----------
__global__ __launch_bounds__(256) void k_split_x(const float* __restrict__ x,
                                                 unsigned short* __restrict__ xhi,
                                                 unsigned short* __restrict__ xlo) {
  const long total = (long)S_LEN * BATCH * DIN / 4;
  long i = (long)blockIdx.x * blockDim.x + threadIdx.x;
  const long stride = (long)gridDim.x * blockDim.x;
  for (; i < total; i += stride) {
    float4 v = ((const float4*)x)[i];
    ushort4 hv, lv;
    hv.x = f2bf(v.x); lv.x = f2bf(v.x - bf2f(hv.x));
    hv.y = f2bf(v.y); lv.y = f2bf(v.y - bf2f(hv.y));
    hv.z = f2bf(v.z); lv.z = f2bf(v.z - bf2f(hv.z));
    hv.w = f2bf(v.w); lv.w = f2bf(v.w - bf2f(hv.w));
    ((ushort4*)xhi)[i] = hv;
    ((ushort4*)xlo)[i] = lv;
  }
}

// ---------- kernel 2: weights -> bf16, bias sum ----------
__global__ __launch_bounds__(256) void k_prep_w(const float* __restrict__ Wih,
                                                const float* __restrict__ Whh,
                                                const float* __restrict__ bih,
                                                const float* __restrict__ bhh,
                                                unsigned short* __restrict__ WihB,
                                                unsigned short* __restrict__ WhhB,
                                                float* __restrict__ bias) {
  int i = blockIdx.x * 256 + threadIdx.x;
  if (i < GATES * DIN) {
    WihB[i] = f2bf(Wih[i]);
    WhhB[i] = f2bf(Whh[i]);
  }
  if (i < GATES) bias[i] = bih[i] + bhh[i];
}

// ---------- kernel 3: pre[t][u][b][gate] = x[t,b,:]·Wih[gate*512+u,:] + biases ----------
#define BM 128
#define BN 128
#define BK 32
#define LDSROW 40

__global__ __launch_bounds__(256) void k_gemm_pre(
    const unsigned short* __restrict__ A,   // WihB [2048][512]
    const unsigned short* __restrict__ Bh,  // xhi  [131072][512]
    const unsigned short* __restrict__ Bl,  // xlo
    const float* __restrict__ bias,
    unsigned short* __restrict__ pre)       // [S][512 u][64 b][4 gate] bf16
{
  __shared__ unsigned short As [BM * LDSROW];
  __shared__ unsigned short Bhs[BM * LDSROW];
  __shared__ unsigned short Bls[BM * LDSROW];

  const int tid  = threadIdx.x;
  const int lane = tid & 63;
  const int wave = tid >> 6;
  const int bm = blockIdx.x & 15;
  const int bn = blockIdx.x >> 4;
  const int wr = wave >> 1, wc = wave & 1;

  f32x4 acc[4][4];
  #pragma unroll
  for (int i = 0; i < 4; ++i)
    #pragma unroll
    for (int j = 0; j < 4; ++j) acc[i][j] = (f32x4){0.f, 0.f, 0.f, 0.f};

  const long arow0 = (long)bm * BM;
  const long brow0 = (long)bn * BN;

  for (int kt = 0; kt < DIN / BK; ++kt) {
    #pragma unroll
    for (int it = 0; it < 2; ++it) {
      int c = tid + it * 256;
      int row = c >> 2, kc = c & 3;
      int lbyte = row * (LDSROW * 2) + kc * 16;
      long ga = (arow0 + row) * 512 + kt * BK + kc * 8;
      long gb = (brow0 + row) * 512 + kt * BK + kc * 8;
      *(short8v*)((char*)As  + lbyte) = *(const short8v*)(A  + ga);
      *(short8v*)((char*)Bhs + lbyte) = *(const short8v*)(Bh + gb);
      *(short8v*)((char*)Bls + lbyte) = *(const short8v*)(Bl + gb);
    }
    __syncthreads();

    short8v a[4], bh[4], bl[4];
    #pragma unroll
    for (int mt = 0; mt < 4; ++mt) {
      int r = wr * 64 + mt * 16 + (lane & 15);
      a[mt] = *(const short8v*)((const char*)As + r * (LDSROW * 2) + (lane >> 4) * 16);
    }
    #pragma unroll
    for (int nt = 0; nt < 4; ++nt) {
      int r = wc * 64 + nt * 16 + (lane & 15);
      bh[nt] = *(const short8v*)((const char*)Bhs + r * (LDSROW * 2) + (lane >> 4) * 16);
      bl[nt] = *(const short8v*)((const char*)Bls + r * (LDSROW * 2) + (lane >> 4) * 16);
    }
    #pragma unroll
    for (int mt = 0; mt < 4; ++mt)
      #pragma unroll
      for (int nt = 0; nt < 4; ++nt) {
        acc[mt][nt] = __builtin_amdgcn_mfma_f32_16x16x32_bf16(a[mt], bh[nt], acc[mt][nt], 0, 0, 0);
        acc[mt][nt] = __builtin_amdgcn_mfma_f32_16x16x32_bf16(a[mt], bl[nt], acc[mt][nt], 0, 0, 0);
      }
    __syncthreads();
  }

  #pragma unroll
  for (int mt = 0; mt < 4; ++mt) {
    #pragma unroll
    for (int j = 0; j < 4; ++j) {
      int m = bm * BM + wr * 64 + mt * 16 + (lane >> 4) * 4 + j;
      int gate = m >> 9;
      int u    = m & 511;
      float bv = bias[m];
      #pragma unroll
      for (int nt = 0; nt < 4; ++nt) {
        int n = bn * BN + wc * 64 + nt * 16 + (lane & 15);
        int t = n >> 6, b = n & 63;
        pre[(((long)t * 512 + u) * 64 + b) * 4 + gate] = f2bf(acc[mt][nt][j] + bv);
      }
    }
  }
}

// ---------- kernel 4: persistent recurrence, swapped-MFMA, tagged self-publishing h ----------
// Identical dataflow to round 8 (verified correct), two fixes:
//  (1) poll loads are sc1-ONLY (device scope -> served at the MALL coherence point;
//      round 8's "sc0 sc1" = system scope went to HBM: 3.5GB FETCH, bandwidth-bound).
//  (2) ldsH swizzled: content[ks][kq][bcol] at byte kq*4096 + bcol*256 +
//      ((ks^bcol)&15)*16 -> writes stay row-contiguous (conflict-free), reads
//      spread over all 32 banks (was a 16-way conflict, 4.7e8 counter).
__global__ __launch_bounds__(256, 1) void k_lstm(
    const unsigned short* __restrict__ pre,   // [S][512][64][4] bf16
    const unsigned short* __restrict__ WhhB,  // [2048][512] bf16
    unsigned* __restrict__ hbuf,              // [2][64 b][512 u] u32 (h|tag)
    float* __restrict__ out)                  // [S*B*H | h_f | c_f]
{
  __shared__ char lds[49152];
  char* ldsW = lds;          // 32KB [ct:2][ks:16][ke:4][r:16][16B]
  char* ldsH = lds + 32768;  // 16KB [kq:4][bcol:16][slot:16][16B], slot=(ks^bcol)&15

  const int tid  = threadIdx.x;
  const int lane = tid & 63;
  const int wave = tid >> 6;          // 0..3
  const int q    = blockIdx.x >> 6;   // batch quad
  const int ublk = blockIdx.x & 63;   // unit octet

  // --- stage W tile into LDS: tile-row r -> (du = r>>2, gate = r&3) ---
  for (int c = tid; c < 2048; c += 256) {
    int ct2 = c >> 10, ks = (c >> 6) & 15, ke = (c >> 4) & 3, r = c & 15;
    long row = (long)(r & 3) * 512 + ublk * 8 + ct2 * 4 + (r >> 2);
    *(short8v*)(ldsW + c * 16) =
        *(const short8v*)(WhhB + row * 512 + ks * 32 + ke * 8);
  }
  __syncthreads();

  // gather assignment: thread covers h[q*16+gb][useg*32 .. +32)
  const int gb   = tid >> 4;          // 0..15  (== bcol it stages for)
  const int useg = tid & 15;          // 0..15  (== ks it stages for)
  const unsigned hbase = (unsigned)((q * 16 + gb) * 512 + useg * 32);

  // compute assignment (waves 0,1): one cell per lane
  const int ct  = wave;               // tile id
  const int b_c = lane & 15;
  const int duc = lane >> 4;
  const int b_g = q * 16 + b_c;
  const int u_g = ublk * 8 + ct * 4 + duc;

  float cst = 0.f;

  #pragma unroll 1
  for (int t = 0; t < S_LEN; ++t) {
    // x-gates (8B, i/f/g/o contiguous) — issued before the poll, hides under it
    ushort4 pv = (ushort4){0, 0, 0, 0};
    if (wave < 2)
      pv = *(const ushort4*)(pre + (((long)t * 512 + u_g) * 64 + b_g) * 4);

    if (t > 0) {
      const unsigned* hb = hbuf + (t & 1) * (64 * 512) + hbase;
      const unsigned tg = (unsigned)t & 0xffffu;
      uint4v a0, a1, a2, a3, a4, a5, a6, a7;
      while (true) {
        // sc1 only: device scope, MALL-served (never HBM)
        asm volatile(
          "global_load_dwordx4 %0, %8, off sc1\n"
          "global_load_dwordx4 %1, %8, off offset:16 sc1\n"
          "global_load_dwordx4 %2, %8, off offset:32 sc1\n"
          "global_load_dwordx4 %3, %8, off offset:48 sc1\n"
          "global_load_dwordx4 %4, %8, off offset:64 sc1\n"
          "global_load_dwordx4 %5, %8, off offset:80 sc1\n"
          "global_load_dwordx4 %6, %8, off offset:96 sc1\n"
          "global_load_dwordx4 %7, %8, off offset:112 sc1\n"
          "s_waitcnt vmcnt(0)"
          : "=&v"(a0), "=&v"(a1), "=&v"(a2), "=&v"(a3),
            "=&v"(a4), "=&v"(a5), "=&v"(a6), "=&v"(a7)
          : "v"(hb)
          : "memory");
        unsigned bad = 0;
        #pragma unroll
        for (int j = 0; j < 4; ++j) {
          bad |= (a0[j] ^ tg) & 0xffffu; bad |= (a1[j] ^ tg) & 0xffffu;
          bad |= (a2[j] ^ tg) & 0xffffu; bad |= (a3[j] ^ tg) & 0xffffu;
          bad |= (a4[j] ^ tg) & 0xffffu; bad |= (a5[j] ^ tg) & 0xffffu;
          bad |= (a6[j] ^ tg) & 0xffffu; bad |= (a7[j] ^ tg) & 0xffffu;
        }
        if (__all(bad == 0)) break;
        __builtin_amdgcn_s_sleep(1);   // backoff: keep retry pressure off the MALL
      }
      // pack hi16 payloads -> bf16-pair dwords; 4 x b128 swizzled LDS writes
      uint4v d0, d1, d2, d3;
      #define PACK_(dv, x, y) \
        dv[0] = (x[0] >> 16) | (x[1] & 0xffff0000u); \
        dv[1] = (x[2] >> 16) | (x[3] & 0xffff0000u); \
        dv[2] = (y[0] >> 16) | (y[1] & 0xffff0000u); \
        dv[3] = (y[2] >> 16) | (y[3] & 0xffff0000u);
      PACK_(d0, a0, a1) PACK_(d1, a2, a3) PACK_(d2, a4, a5) PACK_(d3, a6, a7)
      #undef PACK_
      // content[ks=useg][ke][bcol=gb] -> byte ke*4096 + gb*256 + ((useg^gb)&15)*16
      char* hp = ldsH + gb * 256 + ((useg ^ gb) & 15) * 16;
      *(uint4v*)(hp + 0 * 4096) = d0;
      *(uint4v*)(hp + 1 * 4096) = d1;
      *(uint4v*)(hp + 2 * 4096) = d2;
      *(uint4v*)(hp + 3 * 4096) = d3;
    }

    // barrier #1: H tile ready (LDS-only drain)
    asm volatile("s_waitcnt lgkmcnt(0)" ::: "memory");
    __builtin_amdgcn_s_barrier();
    __builtin_amdgcn_sched_barrier(0);

    f32x4 sum = (f32x4){0.f, 0.f, 0.f, 0.f};
    if (wave < 2 && t > 0) {
      f32x4 e0 = sum, e1 = sum;
      const char* wa = ldsW + ct * 16384 + (lane >> 4) * 256 + (lane & 15) * 16;
      const char* ha = ldsH + (lane >> 4) * 4096 + (lane & 15) * 256;
      const int bcol = lane & 15;
      #pragma unroll
      for (int ks = 0; ks < 16; ++ks) {
        short8v a = *(const short8v*)(wa + ks * 1024);                    // W (A-op)
        short8v b = *(const short8v*)(ha + ((ks ^ bcol) & 15) * 16);      // h (B-op)
        if (ks & 1) e1 = __builtin_amdgcn_mfma_f32_16x16x32_bf16(a, b, e1, 0, 0, 0);
        else        e0 = __builtin_amdgcn_mfma_f32_16x16x32_bf16(a, b, e0, 0, 0, 0);
      }
      sum = e0 + e1;
    }

    // barrier #2: all ldsH reads of step t done -> next step's pack may overwrite
    asm volatile("s_waitcnt lgkmcnt(0)" ::: "memory");
    __builtin_amdgcn_s_barrier();
    __builtin_amdgcn_sched_barrier(0);

    if (wave < 2) {
      // cell update fully in-register: sum[0..3] = (i,f,g,o) pre-activations
      float zi = sum[0] + bf2f(pv.x);
      float zf = sum[1] + bf2f(pv.y);
      float zg = sum[2] + bf2f(pv.z);
      float zo = sum[3] + bf2f(pv.w);
      float ii = 1.f / (1.f + __expf(-zi));
      float ff = 1.f / (1.f + __expf(-zf));
      float e1x = __expf(2.f * fminf(zg, 15.f));
      float gg = (e1x - 1.f) / (e1x + 1.f);
      float oo = 1.f / (1.f + __expf(-zo));
      float cn = ff * cst + ii * gg;
      float e2x = __expf(2.f * fminf(cn, 15.f));
      float tc = (e2x - 1.f) / (e2x + 1.f);
      float hv = oo * tc;
      cst = cn;

      // self-publishing tagged h (payload + tag in one atomic dword, MALL-coherent)
      unsigned hw = ((unsigned)f2bf(hv) << 16) | ((unsigned)(t + 1) & 0xffffu);
      __hip_atomic_store(hbuf + ((t + 1) & 1) * (64 * 512) + b_g * 512 + u_g,
                         hw, __ATOMIC_RELAXED, __HIP_MEMORY_SCOPE_AGENT);

      // out stores off the critical path
      out[(long)t * (BATCH * HID) + (long)b_g * HID + u_g] = hv;
      if (t == S_LEN - 1) {
        long fb = (long)S_LEN * (BATCH * HID);
        out[fb + (long)b_g * HID + u_g] = hv;
        out[fb + BATCH * HID + (long)b_g * HID + u_g] = cn;
      }
    }
  }
}

extern "C" void kernel_launch(void* const* d_in, const int* in_sizes, int n_in,
                              void* d_out, int out_size, void* d_ws, size_t ws_size,
                              hipStream_t stream) {
  const float* x   = (const float*)d_in[0];
  const float* Wih = (const float*)d_in[1];
  const float* Whh = (const float*)d_in[2];
  const float* bih = (const float*)d_in[3];
  const float* bhh = (const float*)d_in[4];
  float* out = (float*)d_out;

  char* ws = (char*)d_ws;
  size_t off = 0;
  auto alloc = [&](size_t bytes) -> char* {
    char* p = ws + off;
    off += (bytes + 255) & ~(size_t)255;
    return p;
  };
  unsigned short* xhi  = (unsigned short*)alloc((size_t)S_LEN * BATCH * DIN * 2);
  unsigned short* xlo  = (unsigned short*)alloc((size_t)S_LEN * BATCH * DIN * 2);
  unsigned short* preb = (unsigned short*)alloc((size_t)S_LEN * GATES * BATCH * 2);
  unsigned short* WihB = (unsigned short*)alloc((size_t)GATES * DIN * 2);
  unsigned short* WhhB = (unsigned short*)alloc((size_t)GATES * DIN * 2);
  float*          bias = (float*)alloc((size_t)GATES * 4);
  unsigned*       hbuf = (unsigned*)alloc((size_t)2 * BATCH * HID * 4);  // 256KB

  // tags must be cleared every launch/replay (step tags would alias otherwise)
  hipMemsetAsync(hbuf, 0, (size_t)2 * BATCH * HID * 4, stream);
  k_split_x<<<8192, 256, 0, stream>>>(x, xhi, xlo);
  k_prep_w<<<4096, 256, 0, stream>>>(Wih, Whh, bih, bhh, WihB, WhhB, bias);
  k_gemm_pre<<<16384, 256, 0, stream>>>(WihB, xhi, xlo, bias, preb);
  k_lstm<<<256, 256, 0, stream>>>(preb, WhhB, hbuf, out);
}

// Round 10
// 11770.429 us; speedup vs baseline: 2.3016x; 2.3016x over previous
//
#include <hip/hip_runtime.h>
#include <hip/hip_bf16.h>

#define S_LEN 2048
#define BATCH 64
#define HID   512
#define GATES 2048   // 4*HID
#define DIN   512

typedef __attribute__((ext_vector_type(8))) short short8v;
typedef __attribute__((ext_vector_type(4))) float f32x4;
typedef __attribute__((ext_vector_type(4))) unsigned uint4v;

__device__ inline unsigned short f2bf(float f) {
  union { float f; unsigned u; } a; a.f = f;
  unsigned r = a.u + 0x7fffu + ((a.u >> 16) & 1u);
  return (unsigned short)(r >> 16);
}
__device__ inline float bf2f(unsigned short h) {
  union { unsigned u; float f; } a; a.u = ((unsigned)h) << 16; return a.f;
}

// ---------- kernel 1: split x (fp32) -> bf16 hi + lo ----------
__global__ __launch_bounds__(256) void k_split_x(const float* __restrict__ x,
                                                 unsigned short* __restrict__ xhi,
                                                 unsigned short* __restrict__ xlo) {
  const long total = (long)S_LEN * BATCH * DIN / 4;
  long i = (long)blockIdx.x * blockDim.x + threadIdx.x;
  const long stride = (long)gridDim.x * blockDim.x;
  for (; i < total; i += stride) {
    float4 v = ((const float4*)x)[i];
    ushort4 hv, lv;
    hv.x = f2bf(v.x); lv.x = f2bf(v.x - bf2f(hv.x));
    hv.y = f2bf(v.y); lv.y = f2bf(v.y - bf2f(hv.y));
    hv.z = f2bf(v.z); lv.z = f2bf(v.z - bf2f(hv.z));
    hv.w = f2bf(v.w); lv.w = f2bf(v.w - bf2f(hv.w));
    ((ushort4*)xhi)[i] = hv;
    ((ushort4*)xlo)[i] = lv;
  }
}

// ---------- kernel 2: weights -> bf16, bias sum ----------
__global__ __launch_bounds__(256) void k_prep_w(const float* __restrict__ Wih,
                                                const float* __restrict__ Whh,
                                                const float* __restrict__ bih,
                                                const float* __restrict__ bhh,
                                                unsigned short* __restrict__ WihB,
                                                unsigned short* __restrict__ WhhB,
                                                float* __restrict__ bias) {
  int i = blockIdx.x * 256 + threadIdx.x;
  if (i < GATES * DIN) {
    WihB[i] = f2bf(Wih[i]);
    WhhB[i] = f2bf(Whh[i]);
  }
  if (i < GATES) bias[i] = bih[i] + bhh[i];
}

// ---------- kernel 3: pre[t][u][b][gate] = x[t,b,:]·Wih[gate*512+u,:] + biases ----------
#define BM 128
#define BN 128
#define BK 32
#define LDSROW 40

__global__ __launch_bounds__(256) void k_gemm_pre(
    const unsigned short* __restrict__ A,   // WihB [2048][512]
    const unsigned short* __restrict__ Bh,  // xhi  [131072][512]
    const unsigned short* __restrict__ Bl,  // xlo
    const float* __restrict__ bias,
    unsigned short* __restrict__ pre)       // [S][512 u][64 b][4 gate] bf16
{
  __shared__ unsigned short As [BM * LDSROW];
  __shared__ unsigned short Bhs[BM * LDSROW];
  __shared__ unsigned short Bls[BM * LDSROW];

  const int tid  = threadIdx.x;
  const int lane = tid & 63;
  const int wave = tid >> 6;
  const int bm = blockIdx.x & 15;
  const int bn = blockIdx.x >> 4;
  const int wr = wave >> 1, wc = wave & 1;

  f32x4 acc[4][4];
  #pragma unroll
  for (int i = 0; i < 4; ++i)
    #pragma unroll
    for (int j = 0; j < 4; ++j) acc[i][j] = (f32x4){0.f, 0.f, 0.f, 0.f};

  const long arow0 = (long)bm * BM;
  const long brow0 = (long)bn * BN;

  for (int kt = 0; kt < DIN / BK; ++kt) {
    #pragma unroll
    for (int it = 0; it < 2; ++it) {
      int c = tid + it * 256;
      int row = c >> 2, kc = c & 3;
      int lbyte = row * (LDSROW * 2) + kc * 16;
      long ga = (arow0 + row) * 512 + kt * BK + kc * 8;
      long gb = (brow0 + row) * 512 + kt * BK + kc * 8;
      *(short8v*)((char*)As  + lbyte) = *(const short8v*)(A  + ga);
      *(short8v*)((char*)Bhs + lbyte) = *(const short8v*)(Bh + gb);
      *(short8v*)((char*)Bls + lbyte) = *(const short8v*)(Bl + gb);
    }
    __syncthreads();

    short8v a[4], bh[4], bl[4];
    #pragma unroll
    for (int mt = 0; mt < 4; ++mt) {
      int r = wr * 64 + mt * 16 + (lane & 15);
      a[mt] = *(const short8v*)((const char*)As + r * (LDSROW * 2) + (lane >> 4) * 16);
    }
    #pragma unroll
    for (int nt = 0; nt < 4; ++nt) {
      int r = wc * 64 + nt * 16 + (lane & 15);
      bh[nt] = *(const short8v*)((const char*)Bhs + r * (LDSROW * 2) + (lane >> 4) * 16);
      bl[nt] = *(const short8v*)((const char*)Bls + r * (LDSROW * 2) + (lane >> 4) * 16);
    }
    #pragma unroll
    for (int mt = 0; mt < 4; ++mt)
      #pragma unroll
      for (int nt = 0; nt < 4; ++nt) {
        acc[mt][nt] = __builtin_amdgcn_mfma_f32_16x16x32_bf16(a[mt], bh[nt], acc[mt][nt], 0, 0, 0);
        acc[mt][nt] = __builtin_amdgcn_mfma_f32_16x16x32_bf16(a[mt], bl[nt], acc[mt][nt], 0, 0, 0);
      }
    __syncthreads();
  }

  #pragma unroll
  for (int mt = 0; mt < 4; ++mt) {
    #pragma unroll
    for (int j = 0; j < 4; ++j) {
      int m = bm * BM + wr * 64 + mt * 16 + (lane >> 4) * 4 + j;
      int gate = m >> 9;
      int u    = m & 511;
      float bv = bias[m];
      #pragma unroll
      for (int nt = 0; nt < 4; ++nt) {
        int n = bn * BN + wc * 64 + nt * 16 + (lane & 15);
        int t = n >> 6, b = n & 63;
        pre[(((long)t * 512 + u) * 64 + b) * 4 + gate] = f2bf(acc[mt][nt][j] + bv);
      }
    }
  }
}

// ---------- kernel 4: persistent recurrence ----------
// 256 blocks x 256 threads. Quad q = bid>>6 owns batches [q*16,+16); ublk = bid&63
// owns units [ublk*8,+8). Swapped MFMA (r8/r9-verified): waves 0-1 each compute a
// gate-complete 16x16 tile; acc[0..3] = (i,f,g,o) of one cell — no transpose, no
// K-split reduce. W_hh in LDS; ldsH XOR-swizzled (r9: zero bank conflicts).
// Sync = r4's measured-fastest protocol: per-block flags, __hip_atomic AGENT
// loads/stores ONLY (the compiler path showed 0.8-1.6GB FETCH vs 3.5GB for
// hand-rolled sc1 asm), publish after vmcnt(0)+barrier, own-block exempt.
// h packed 2 units/u32 -> gather is 8 x u64 atomic loads (64B/thread).
// Waves 2-3 heat the VALU during the MFMA phase; poll loops burn FMA chains:
// if the ~6us/step floor is DPM downclock, this lifts it; if not, it's ~free.
__global__ __launch_bounds__(256, 1) void k_lstm(
    const unsigned short* __restrict__ pre,   // [S][512][64][4] bf16
    const unsigned short* __restrict__ WhhB,  // [2048][512] bf16
    unsigned* __restrict__ hbuf,              // [2][64 b][256] u32 (2 bf16 units)
    unsigned* __restrict__ flags,             // [4][64]
    float* __restrict__ out)                  // [S*B*H | h_f | c_f]
{
  __shared__ char lds[49152];
  char* ldsW = lds;          // 32KB [ct:2][ks:16][ke:4][r:16][16B]
  char* ldsH = lds + 32768;  // 16KB [ke:4][b:16][slot:16][16B], slot=(ks^b)&15

  const int tid  = threadIdx.x;
  const int lane = tid & 63;
  const int wave = tid >> 6;          // 0..3
  const int q    = blockIdx.x >> 6;   // batch quad
  const int ublk = blockIdx.x & 63;   // unit octet

  // --- stage W tile into LDS: tile-row r -> (du = r>>2, gate = r&3) ---
  for (int c = tid; c < 2048; c += 256) {
    int ct2 = c >> 10, ks = (c >> 6) & 15, ke = (c >> 4) & 3, r = c & 15;
    long row = (long)(r & 3) * 512 + ublk * 8 + ct2 * 4 + (r >> 2);
    *(short8v*)(ldsW + c * 16) =
        *(const short8v*)(WhhB + row * 512 + ks * 32 + ke * 8);
  }
  __syncthreads();

  // gather assignment: thread stages h[q*16+gb][useg*32 .. +32) (packed u32s)
  const int gb   = tid >> 4;          // 0..15 (batch row staged)
  const int useg = tid & 15;          // 0..15 (== ks staged)

  // cell assignment (waves 0,1): one cell per lane
  const int ct  = wave;
  const int b_c = lane & 15;
  const int duc = lane >> 4;
  const int b_g = q * 16 + b_c;
  const int u_g = ublk * 8 + ct * 4 + duc;

  float cst = 0.f;
  float heat = (float)tid * 1e-3f + 1.0f;

  #pragma unroll 1
  for (int t = 0; t < S_LEN; ++t) {
    // x-gates (8B, i/f/g/o contiguous) — issued before the poll, hides under it
    ushort4 pv = (ushort4){0, 0, 0, 0};
    if (wave < 2)
      pv = *(const ushort4*)(pre + (((long)t * 512 + u_g) * 64 + b_g) * 4);

    if (t > 0) {
      // flag poll (r4 protocol): lane L watches flag L; own block exempt
      {
        const unsigned* fp = &flags[q * 64 + lane];
        int v = (lane == ublk) ? 0x7fffffff
                               : (int)__hip_atomic_load(fp, __ATOMIC_RELAXED,
                                                        __HIP_MEMORY_SCOPE_AGENT);
        while (!__all(v >= t)) {
          #pragma unroll
          for (int z = 0; z < 16; ++z) heat = __builtin_fmaf(heat, 1.000001f, 1e-6f);
          asm volatile("" : "+v"(heat));
          v = (lane == ublk) ? 0x7fffffff
                             : (int)__hip_atomic_load(fp, __ATOMIC_RELAXED,
                                                      __HIP_MEMORY_SCOPE_AGENT);
        }
      }
      asm volatile("" ::: "memory");
      // gather: 8 x u64 agent-atomic loads (64B), then 4 swizzled b128 LDS writes
      const unsigned long long* hb = (const unsigned long long*)
          (hbuf + (t & 1) * (64 * 256) + (q * 16 + gb) * 256 + useg * 16);
      unsigned long long a[8];
      #pragma unroll
      for (int j = 0; j < 8; ++j)
        a[j] = __hip_atomic_load(hb + j, __ATOMIC_RELAXED, __HIP_MEMORY_SCOPE_AGENT);
      char* hp = ldsH + gb * 256 + ((useg ^ gb) & 15) * 16;
      #pragma unroll
      for (int ke = 0; ke < 4; ++ke) {
        uint4v dv;
        dv[0] = (unsigned)(a[ke * 2]);
        dv[1] = (unsigned)(a[ke * 2] >> 32);
        dv[2] = (unsigned)(a[ke * 2 + 1]);
        dv[3] = (unsigned)(a[ke * 2 + 1] >> 32);
        *(uint4v*)(hp + ke * 4096) = dv;
      }
    }

    // barrier #1: H tile ready (LDS-only drain)
    asm volatile("s_waitcnt lgkmcnt(0)" ::: "memory");
    __builtin_amdgcn_s_barrier();
    __builtin_amdgcn_sched_barrier(0);

    f32x4 sum = (f32x4){0.f, 0.f, 0.f, 0.f};
    if (wave < 2) {
      if (t > 0) {
        f32x4 e0 = sum, e1 = sum;
        const char* wa = ldsW + ct * 16384 + (lane >> 4) * 256 + (lane & 15) * 16;
        const char* ha = ldsH + (lane >> 4) * 4096 + (lane & 15) * 256;
        const int bcol = lane & 15;
        #pragma unroll
        for (int ks = 0; ks < 16; ++ks) {
          short8v av = *(const short8v*)(wa + ks * 1024);               // W (A-op)
          short8v bv = *(const short8v*)(ha + ((ks ^ bcol) & 15) * 16); // h (B-op)
          if (ks & 1) e1 = __builtin_amdgcn_mfma_f32_16x16x32_bf16(av, bv, e1, 0, 0, 0);
          else        e0 = __builtin_amdgcn_mfma_f32_16x16x32_bf16(av, bv, e0, 0, 0, 0);
        }
        sum = e0 + e1;
      }
    } else {
      // heater: keep the CU's VALU activity up under the MFMA phase
      #pragma unroll
      for (int z = 0; z < 256; ++z) heat = __builtin_fmaf(heat, 1.0000001f, 1e-7f);
      asm volatile("" : "+v"(heat));
    }

    // barrier #2: all ldsH reads of step t done -> t+1 staging may overwrite
    asm volatile("s_waitcnt lgkmcnt(0)" ::: "memory");
    __builtin_amdgcn_s_barrier();
    __builtin_amdgcn_sched_barrier(0);

    float hv = 0.f, cn = 0.f;
    if (wave < 2) {
      // cell update fully in-register: sum[0..3] = (i,f,g,o)
      float zi = sum[0] + bf2f(pv.x);
      float zf = sum[1] + bf2f(pv.y);
      float zg = sum[2] + bf2f(pv.z);
      float zo = sum[3] + bf2f(pv.w);
      float ii = 1.f / (1.f + __expf(-zi));
      float ff = 1.f / (1.f + __expf(-zf));
      float e1x = __expf(2.f * fminf(zg, 15.f));
      float gg = (e1x - 1.f) / (e1x + 1.f);
      float oo = 1.f / (1.f + __expf(-zo));
      cn = ff * cst + ii * gg;
      float e2x = __expf(2.f * fminf(cn, 15.f));
      float tc = (e2x - 1.f) / (e2x + 1.f);
      hv = oo * tc;
      cst = cn;

      // publish h: 2 units packed per u32 (partner = lane^16 -> duc pair)
      unsigned short h16 = f2bf(hv);
      unsigned prt = (unsigned)__shfl_xor((int)(unsigned)h16, 16);
      if (!(lane & 16)) {   // duc even
        unsigned w = (unsigned)h16 | (prt << 16);
        __hip_atomic_store(hbuf + ((t + 1) & 1) * (64 * 256) + b_g * 256
                               + ublk * 4 + ct * 2 + (duc >> 1),
                           w, __ATOMIC_RELAXED, __HIP_MEMORY_SCOPE_AGENT);
      }
    }

    // release: drain h stores to the coherence point, then publish flag
    asm volatile("s_waitcnt vmcnt(0)" ::: "memory");
    __syncthreads();
    if (tid == 0)
      __hip_atomic_store(&flags[q * 64 + ublk], (unsigned)(t + 1),
                         __ATOMIC_RELAXED, __HIP_MEMORY_SCOPE_AGENT);

    // out stores AFTER flag publish: off the critical path
    if (wave < 2) {
      out[(long)t * (BATCH * HID) + (long)b_g * HID + u_g] = hv;
      if (t == S_LEN - 1) {
        long fb = (long)S_LEN * (BATCH * HID);
        out[fb + (long)b_g * HID + u_g] = hv;
        out[fb + BATCH * HID + (long)b_g * HID + u_g] = cn;
      }
    }
  }
}

extern "C" void kernel_launch(void* const* d_in, const int* in_sizes, int n_in,
                              void* d_out, int out_size, void* d_ws, size_t ws_size,
                              hipStream_t stream) {
  const float* x   = (const float*)d_in[0];
  const float* Wih = (const float*)d_in[1];
  const float* Whh = (const float*)d_in[2];
  const float* bih = (const float*)d_in[3];
  const float* bhh = (const float*)d_in[4];
  float* out = (float*)d_out;

  char* ws = (char*)d_ws;
  size_t off = 0;
  auto alloc = [&](size_t bytes) -> char* {
    char* p = ws + off;
    off += (bytes + 255) & ~(size_t)255;
    return p;
  };
  unsigned short* xhi  = (unsigned short*)alloc((size_t)S_LEN * BATCH * DIN * 2);
  unsigned short* xlo  = (unsigned short*)alloc((size_t)S_LEN * BATCH * DIN * 2);
  unsigned short* preb = (unsigned short*)alloc((size_t)S_LEN * GATES * BATCH * 2);
  unsigned short* WihB = (unsigned short*)alloc((size_t)GATES * DIN * 2);
  unsigned short* WhhB = (unsigned short*)alloc((size_t)GATES * DIN * 2);
  float*          bias = (float*)alloc((size_t)GATES * 4);
  unsigned*       hbuf = (unsigned*)alloc((size_t)2 * 64 * 256 * 4);   // 128KB packed
  unsigned*       flg  = (unsigned*)alloc((size_t)4 * 64 * 4);

  hipMemsetAsync(flg, 0, (size_t)4 * 64 * 4, stream);   // replay-safe (r4-proven)
  k_split_x<<<8192, 256, 0, stream>>>(x, xhi, xlo);
  k_prep_w<<<4096, 256, 0, stream>>>(Wih, Whh, bih, bhh, WihB, WhhB, bias);
  k_gemm_pre<<<16384, 256, 0, stream>>>(WihB, xhi, xlo, bias, preb);
  k_lstm<<<256, 256, 0, stream>>>(preb, WhhB, hbuf, flg, out);
}